// Round 4
// baseline (2527.561 us; speedup 1.0000x reference)
//
#include <hip/hip_runtime.h>
#include <math.h>

// FusionShiftingGraph: two 4-layer no-residual transformer stacks + final LN.
// Round 4: barrier-free MFMA attention. 16-row q-tiles; 4 waves split key
// tiles with private online-softmax state; exact LSE merge via LDS at the
// end. K/V fragments loaded directly from pre-transposed global bf16 planes
// (L2-resident) -- no LDS staging, no barriers, no 8-way-conflict ds_reads.
// K pre-converted once/layer to unpadded [bh][n][d96] planes (= x0 region).
// GEMMs unchanged (3-plane split-bf16 MFMA, r2-proven).
//
// Segments: [0,50) [50,425) [425,800).  B=8, N=800, D=768, H=8, hd=96.

#define NTOK 800
#define ROWS 6400          // B*N
#define DIM 768
#define QKVD 2304
#define HD 96
#define KPAD 832           // padded key space: [0,64)+[64,448)+[448,832)

typedef unsigned short u16;
typedef unsigned int u32;
using bf16x8 = __attribute__((ext_vector_type(8))) short;   // 8 bf16 (4 VGPRs)
using f32x4  = __attribute__((ext_vector_type(4))) float;

__device__ __forceinline__ u16 f2bf(float x) {            // RNE fp32->bf16
  union { float f; u32 u; } v; v.f = x;
  u32 r = v.u + 0x7fffu + ((v.u >> 16) & 1u);
  return (u16)(r >> 16);
}
__device__ __forceinline__ float bf2f(u16 h) {
  union { u32 u; float f; } v; v.u = ((u32)h) << 16;
  return v.f;
}
__device__ __forceinline__ u32 asu(float x) { union { float f; u32 u; } v; v.f = x; return v.u; }
__device__ __forceinline__ float asf(u32 x) { union { u32 u; float f; } v; v.u = x; return v.f; }
__device__ __forceinline__ void async16(const u16* g, u16* l) {
  __builtin_amdgcn_global_load_lds((const __attribute__((address_space(1))) u32*)g,
                                   (__attribute__((address_space(3))) u32*)l,
                                   16, 0, 0);
}

// ---------------------------------------------------------------- embed
__global__ __launch_bounds__(256) void k_embed(const float* __restrict__ s0,
                                               const float* __restrict__ s1,
                                               const float* __restrict__ s2,
                                               float* __restrict__ x) {
  int row = blockIdx.x;            // 0..6399
  int b = row / NTOK, n = row % NTOK;
  const float* src; int ln;
  if (n < 50)       { src = s0 + ((size_t)b * 50  + n)         * DIM; ln = n; }
  else if (n < 425) { src = s1 + ((size_t)b * 375 + (n - 50))  * DIM; ln = n - 50; }
  else              { src = s2 + ((size_t)b * 375 + (n - 425)) * DIM; ln = n - 425; }
  double p = (double)(ln + 2);     // fairseq: positions start at padding_idx+1=2
  const double negk = -(9.210340371976184 / 383.0);  // -ln(10000)/(half-1)
  float* dst = x + (size_t)row * DIM;
  for (int i = 0; i < 3; i++) {
    int d = threadIdx.x + (i << 8);
    int dd = (d < 384) ? d : d - 384;
    double ang = p * exp((double)dd * negk);
    float pe = (float)((d < 384) ? sin(ang) : cos(ang));
    dst[d] = 27.712812921102035f * src[d] + pe;   // sqrt(768)*s + pe
  }
}

// ------------------------------------------------- fp32 -> (hi,lo) bf16 planes
__global__ __launch_bounds__(256) void k_conv(const float* __restrict__ x,
                                              u16* __restrict__ hi,
                                              u16* __restrict__ lo, int n8) {
  int i = blockIdx.x * 256 + threadIdx.x;   // 8 elems / thread
  if (i >= n8) return;
  float4 a = ((const float4*)x)[i * 2];
  float4 b = ((const float4*)x)[i * 2 + 1];
  float v[8] = {a.x, a.y, a.z, a.w, b.x, b.y, b.z, b.w};
  u32 hp[4], lp[4];
#pragma unroll
  for (int j = 0; j < 4; j++) {
    u16 h0 = f2bf(v[2 * j]), h1 = f2bf(v[2 * j + 1]);
    u16 l0 = f2bf(v[2 * j] - bf2f(h0));
    u16 l1 = f2bf(v[2 * j + 1] - bf2f(h1));
    hp[j] = (u32)h0 | ((u32)h1 << 16);
    lp[j] = (u32)l0 | ((u32)l1 << 16);
  }
  ((uint4*)hi)[i] = make_uint4(hp[0], hp[1], hp[2], hp[3]);
  ((uint4*)lo)[i] = make_uint4(lp[0], lp[1], lp[2], lp[3]);
}

// ------------------------------------------- split-bf16 MFMA NT GEMM (r2)
__global__ __launch_bounds__(256) void k_gemm_mfma(
    const u16* __restrict__ Ah, const u16* __restrict__ Al,
    const u16* __restrict__ Bh, const u16* __restrict__ Bl,
    const float* __restrict__ bias, float* __restrict__ C,
    int M, int N, int K) {
  __shared__ __align__(16) u16 sm[4 * 4096];       // Ah | Al | Bh | Bl
  int tid = threadIdx.x;
  int wave = tid >> 6, lane = tid & 63;
  int m0 = blockIdx.y << 7, n0 = blockIdx.x << 7;
  int wr = wave >> 1, wc = wave & 1;
  int l15 = lane & 15, quad = lane >> 4;

  f32x4 acc[4][4];
#pragma unroll
  for (int i = 0; i < 4; i++)
#pragma unroll
    for (int j = 0; j < 4; j++) acc[i][j] = (f32x4){0.f, 0.f, 0.f, 0.f};

  const u16* srcs[4] = {Ah + (size_t)m0 * K, Al + (size_t)m0 * K,
                        Bh + (size_t)n0 * K, Bl + (size_t)n0 * K};
  int li0 = wave * 64 + lane;
  int li1 = li0 + 256;
  int r0 = li0 >> 2, q0 = (li0 & 3) ^ ((r0 >> 1) & 3);
  int r1 = li1 >> 2, q1 = (li1 & 3) ^ ((r1 >> 1) & 3);
  size_t g0 = (size_t)r0 * K + q0 * 8;
  size_t g1 = (size_t)r1 * K + q1 * 8;

  for (int kt = 0; kt < K; kt += 32) {
    __syncthreads();
#pragma unroll
    for (int ri = 0; ri < 4; ri++) {
      const u16* s = srcs[ri] + kt;
      async16(s + g0, &sm[ri * 4096 + wave * 512]);
      async16(s + g1, &sm[ri * 4096 + 2048 + wave * 512]);
    }
    __syncthreads();

    bf16x8 ah[4], al[4], bh[4], bl[4];
#pragma unroll
    for (int i = 0; i < 4; i++) {
      int ra = wr * 64 + i * 16 + l15;
      int qa = (quad ^ ((ra >> 1) & 3)) * 8;
      ah[i] = *(const bf16x8*)&sm[0 * 4096 + ra * 32 + qa];
      al[i] = *(const bf16x8*)&sm[1 * 4096 + ra * 32 + qa];
      int rb = wc * 64 + i * 16 + l15;
      int qb = (quad ^ ((rb >> 1) & 3)) * 8;
      bh[i] = *(const bf16x8*)&sm[2 * 4096 + rb * 32 + qb];
      bl[i] = *(const bf16x8*)&sm[3 * 4096 + rb * 32 + qb];
    }
#pragma unroll
    for (int i = 0; i < 4; i++)
#pragma unroll
      for (int j = 0; j < 4; j++) {
        acc[i][j] = __builtin_amdgcn_mfma_f32_16x16x32_bf16(ah[i], bh[j], acc[i][j], 0, 0, 0);
        acc[i][j] = __builtin_amdgcn_mfma_f32_16x16x32_bf16(ah[i], bl[j], acc[i][j], 0, 0, 0);
        acc[i][j] = __builtin_amdgcn_mfma_f32_16x16x32_bf16(al[i], bh[j], acc[i][j], 0, 0, 0);
      }
  }
#pragma unroll
  for (int i = 0; i < 4; i++) {
    int row0 = m0 + wr * 64 + i * 16 + quad * 4;
#pragma unroll
    for (int j = 0; j < 4; j++) {
      int col = n0 + wc * 64 + j * 16 + l15;
      float bv = bias[col];
#pragma unroll
      for (int r = 0; r < 4; r++)
        C[(size_t)(row0 + r) * N + col] = acc[i][j][r] + bv;
    }
  }
}

// ------------------------------------------- K/V conversion per layer
// Kt (unpadded): [bh][n 800][d 96] trunc 2-plane bf16  (straight convert)
// Vt (padded):   [bh][d 96][key' 832] trunc 2-plane bf16 (transpose via LDS)
// Grid: 13 (64-key chunks) x 64 bh.
__global__ __launch_bounds__(256) void k_convkv(const float* __restrict__ qkv,
                                                u16* __restrict__ Kthi,
                                                u16* __restrict__ Ktlo,
                                                u16* __restrict__ Vthi,
                                                u16* __restrict__ Vtlo) {
  int ck = blockIdx.x % 13;
  int bh = blockIdx.x / 13;
  int b = bh >> 3, h = bh & 7;
  int kt = ck << 6;
  int ve  = kt < 64 ? 50 : kt < 448 ? 439 : 823;   // valid end (padded coords)
  int off = kt < 64 ? 0  : kt < 448 ? 14  : 23;    // key' - off = real n
  __shared__ float Ls[96 * 68];
  int tid = threadIdx.x;
  size_t base = (size_t)b * NTOK;

  // ---- K: straight convert (no transpose)
#pragma unroll
  for (int i = 0; i < 6; i++) {
    int c = i * 256 + tid;            // 1536 = 64 keys x 24 d-chunks
    int key = c / 24, dc = c - key * 24;
    int kp = kt + key;
    if (kp < ve) {
      int n = kp - off;
      float4 v = *(const float4*)(qkv + (base + n) * QKVD + DIM + h * HD + dc * 4);
      u32 b0 = asu(v.x), b1 = asu(v.y), b2 = asu(v.z), b3 = asu(v.w);
      u32 h01 = (b0 >> 16) | (b1 & 0xffff0000u);
      u32 h23 = (b2 >> 16) | (b3 & 0xffff0000u);
      float l0 = v.x - asf(b0 & 0xffff0000u);
      float l1 = v.y - asf(b1 & 0xffff0000u);
      float l2 = v.z - asf(b2 & 0xffff0000u);
      float l3 = v.w - asf(b3 & 0xffff0000u);
      u32 lo01 = (asu(l0) >> 16) | (asu(l1) & 0xffff0000u);
      u32 lo23 = (asu(l2) >> 16) | (asu(l3) & 0xffff0000u);
      size_t go = ((size_t)bh * 800 + n) * 96 + dc * 4;
      *(uint2*)(Kthi + go) = make_uint2(h01, h23);
      *(uint2*)(Ktlo + go) = make_uint2(lo01, lo23);
    }
  }

  // ---- V: transpose via LDS (r3-proven)
#pragma unroll
  for (int i = 0; i < 6; i++) {
    int c = i * 256 + tid;            // 1536 = 64 keys x 24 d-chunks
    int key = c / 24, dc = c - key * 24;
    int kp = kt + key;
    float4 v = make_float4(0.f, 0.f, 0.f, 0.f);
    if (kp < ve) {
      int n = kp - off;
      v = *(const float4*)(qkv + (base + n) * QKVD + 2 * DIM + h * HD + dc * 4);
    }
    Ls[(dc * 4 + 0) * 68 + key] = v.x;
    Ls[(dc * 4 + 1) * 68 + key] = v.y;
    Ls[(dc * 4 + 2) * 68 + key] = v.z;
    Ls[(dc * 4 + 3) * 68 + key] = v.w;
  }
  __syncthreads();
#pragma unroll
  for (int i = 0; i < 3; i++) {
    int c = i * 256 + tid;            // 768 = 96 d x 8 key-chunks
    int d = c >> 3, ch = c & 7;
    float4 a = *(const float4*)&Ls[d * 68 + ch * 8];
    float4 e = *(const float4*)&Ls[d * 68 + ch * 8 + 4];
    float xs[8] = {a.x, a.y, a.z, a.w, e.x, e.y, e.z, e.w};
    u32 hp[4], lp[4];
#pragma unroll
    for (int j = 0; j < 4; j++) {
      u32 b0 = asu(xs[2 * j]), b1 = asu(xs[2 * j + 1]);
      hp[j] = (b0 >> 16) | (b1 & 0xffff0000u);
      float l0 = xs[2 * j] - asf(b0 & 0xffff0000u);
      float l1 = xs[2 * j + 1] - asf(b1 & 0xffff0000u);
      lp[j] = (asu(l0) >> 16) | (asu(l1) & 0xffff0000u);
    }
    size_t go = ((size_t)bh * 96 + d) * KPAD + kt + ch * 8;
    *(uint4*)(Vthi + go) = make_uint4(hp[0], hp[1], hp[2], hp[3]);
    *(uint4*)(Vtlo + go) = make_uint4(lp[0], lp[1], lp[2], lp[3]);
  }
}

// ------------------------------------------- barrier-free MFMA attention
// Block: 16 q-rows, 4 waves splitting key tiles (private online-softmax
// state), exact LSE merge via LDS at the end. K/V fragments loaded directly
// from global planes (L2-resident). No barriers in the main loop.
__global__ __launch_bounds__(256) void k_attn(const float* __restrict__ qkv,
                                              const u16* __restrict__ Kthi,
                                              const u16* __restrict__ Ktlo,
                                              const u16* __restrict__ Vthi,
                                              const u16* __restrict__ Vtlo,
                                              float* __restrict__ outp,
                                              int intra) {
  int qt = blockIdx.x % 52;
  int bh = blockIdx.x / 52;
  int b = bh >> 3, h = bh & 7;

  int seg, q0, qlen;
  if (qt < 4)       { seg = 0; q0 = qt << 4;                qlen = (50 - q0 < 16) ? 50 - q0 : 16; }
  else if (qt < 28) { seg = 1; q0 = 50 + ((qt - 4) << 4);   qlen = (425 - q0 < 16) ? 425 - q0 : 16; }
  else              { seg = 2; q0 = 425 + ((qt - 28) << 4); qlen = (800 - q0 < 16) ? 800 - q0 : 16; }

  // key ranges in padded coords
  int r0s, r0e, r1s = 0, r1e = 0;
  if (intra) {
    r0s = (seg == 0) ? 0 : (seg == 1) ? 64 : 448;
    r0e = (seg == 0) ? 64 : (seg == 1) ? 448 : 832;
  } else {
    if (seg == 0)      { r0s = 64; r0e = 832; }
    else if (seg == 1) { r0s = 0;  r0e = 64;  r1s = 448; r1e = 832; }
    else               { r0s = 0;  r0e = 448; }
  }
  int n0t = (r0e - r0s) >> 5, n1t = (r1e - r1s) >> 5, nkt = n0t + n1t;

  // LDS: per-wave 1600-float region (union: P-transpose u32[16][36] during
  // loop; merged O fp32[16][100] after) + per-wave (m,l) exchange.
  __shared__ __align__(16) float U[4 * 1600];
  __shared__ float sOm[4][16], sOl[4][16];

  int tid = threadIdx.x;
  int w = tid >> 6, lane = tid & 63, l15 = lane & 15, quad = lane >> 4;
  size_t base = (size_t)b * NTOK;
  const float sm0 = 0.10206207261596575f;   // 96^-0.5

  // ---- Q fragments (RNE 2-plane, pre-scaled) — same rows for all 4 waves
  bf16x8 qh[3], ql[3];
  {
    int q = q0 + l15; if (q > 799) q = 799;
    const float* qp = qkv + (base + q) * QKVD + h * HD;
#pragma unroll
    for (int df = 0; df < 3; df++) {
      float4 x0v = *(const float4*)(qp + df * 32 + quad * 8);
      float4 x1v = *(const float4*)(qp + df * 32 + quad * 8 + 4);
      float xs[8] = {x0v.x, x0v.y, x0v.z, x0v.w, x1v.x, x1v.y, x1v.z, x1v.w};
#pragma unroll
      for (int j = 0; j < 8; j++) {
        float x = xs[j] * sm0;
        u16 hu = f2bf(x);
        u16 lu = f2bf(x - bf2f(hu));
        qh[df][j] = (short)hu; ql[df][j] = (short)lu;
      }
    }
  }

  f32x4 oacc[6];
#pragma unroll
  for (int c = 0; c < 6; c++) oacc[c] = (f32x4){0.f, 0.f, 0.f, 0.f};
  float m_i[4], l_i[4];
#pragma unroll
  for (int r = 0; r < 4; r++) { m_i[r] = -1e30f; l_i[r] = 0.f; }

  u32* sPw = (u32*)U + w * 1600;
  const u16* Kbh_h = Kthi + (size_t)bh * 800 * 96;
  const u16* Kbh_l = Ktlo + (size_t)bh * 800 * 96;
  const u16* Vbh_h = Vthi + (size_t)bh * 96 * KPAD;
  const u16* Vbh_l = Vtlo + (size_t)bh * 96 * KPAD;

  for (int it = w; it < nkt; it += 4) {
    int kt = (it < n0t) ? (r0s + (it << 5)) : (r1s + ((it - n0t) << 5));
    int ve  = kt < 64 ? 50 : kt < 448 ? 439 : 823;
    int off = kt < 64 ? 0  : kt < 448 ? 14  : 23;

    // ---- S = Q K^T via MFMA, K frags direct from global planes
    f32x4 Sf[2];
#pragma unroll
    for (int h2 = 0; h2 < 2; h2++) {
      int kp = kt + h2 * 16 + l15;
      int n = kp - off; if (n > 799) n = 799;
      const u16* kbh = Kbh_h + (size_t)n * 96;
      const u16* kbl = Kbh_l + (size_t)n * 96;
      f32x4 s = (f32x4){0.f, 0.f, 0.f, 0.f};
#pragma unroll
      for (int df = 0; df < 3; df++) {
        bf16x8 kh = *(const bf16x8*)(kbh + df * 32 + quad * 8);
        bf16x8 kl = *(const bf16x8*)(kbl + df * 32 + quad * 8);
        s = __builtin_amdgcn_mfma_f32_16x16x32_bf16(qh[df], kh, s, 0, 0, 0);
        s = __builtin_amdgcn_mfma_f32_16x16x32_bf16(ql[df], kh, s, 0, 0, 0);
        s = __builtin_amdgcn_mfma_f32_16x16x32_bf16(qh[df], kl, s, 0, 0, 0);
      }
      Sf[h2] = s;
    }
    if (kt + l15 >= ve)      Sf[0] = (f32x4){-1e30f, -1e30f, -1e30f, -1e30f};
    if (kt + 16 + l15 >= ve) Sf[1] = (f32x4){-1e30f, -1e30f, -1e30f, -1e30f};

    // ---- online softmax (per-wave private state)
    float mx[4], al[4], ps0[4], ps1[4], rs[4];
#pragma unroll
    for (int r = 0; r < 4; r++) mx[r] = fmaxf(Sf[0][r], Sf[1][r]);
#pragma unroll
    for (int o = 1; o < 16; o <<= 1)
#pragma unroll
      for (int r = 0; r < 4; r++) mx[r] = fmaxf(mx[r], __shfl_xor(mx[r], o, 64));
#pragma unroll
    for (int r = 0; r < 4; r++) {
      float mn = fmaxf(m_i[r], mx[r]);
      al[r] = __expf(m_i[r] - mn);
      m_i[r] = mn;
      ps0[r] = __expf(Sf[0][r] - mn);
      ps1[r] = __expf(Sf[1][r] - mn);
      rs[r] = ps0[r] + ps1[r];
    }
#pragma unroll
    for (int o = 1; o < 16; o <<= 1)
#pragma unroll
      for (int r = 0; r < 4; r++) rs[r] += __shfl_xor(rs[r], o, 64);
#pragma unroll
    for (int r = 0; r < 4; r++) l_i[r] = l_i[r] * al[r] + rs[r];

    // ---- pack P (trunc 2-plane), transpose via per-wave LDS (intra-wave)
#pragma unroll
    for (int r = 0; r < 4; r++) {
      u32 b0 = asu(ps0[r]);
      float lo0 = ps0[r] - asf(b0 & 0xffff0000u);
      sPw[(quad * 4 + r) * 36 + l15] = (b0 >> 16) | (asu(lo0) & 0xffff0000u);
      u32 b1 = asu(ps1[r]);
      float lo1 = ps1[r] - asf(b1 & 0xffff0000u);
      sPw[(quad * 4 + r) * 36 + 16 + l15] = (b1 >> 16) | (asu(lo1) & 0xffff0000u);
    }
    asm volatile("" ::: "memory");
    uint4 t0 = *(const uint4*)&sPw[l15 * 36 + quad * 8];
    uint4 t1 = *(const uint4*)&sPw[l15 * 36 + quad * 8 + 4];
    u32 tt[8] = {t0.x, t0.y, t0.z, t0.w, t1.x, t1.y, t1.z, t1.w};
    bf16x8 ph, pl;
#pragma unroll
    for (int j = 0; j < 8; j++) {
      ph[j] = (short)(tt[j] & 0xffffu);
      pl[j] = (short)(tt[j] >> 16);
    }

    // ---- rescale O, then O += P V (V frags direct from global planes)
    f32x4 alv = {al[0], al[1], al[2], al[3]};
#pragma unroll
    for (int c = 0; c < 6; c++) oacc[c] *= alv;
#pragma unroll
    for (int c = 0; c < 6; c++) {
      size_t vo = (size_t)(c * 16 + l15) * KPAD + kt + quad * 8;
      bf16x8 vh = *(const bf16x8*)(Vbh_h + vo);
      bf16x8 vl = *(const bf16x8*)(Vbh_l + vo);
      oacc[c] = __builtin_amdgcn_mfma_f32_16x16x32_bf16(ph, vh, oacc[c], 0, 0, 0);
      oacc[c] = __builtin_amdgcn_mfma_f32_16x16x32_bf16(ph, vl, oacc[c], 0, 0, 0);
      oacc[c] = __builtin_amdgcn_mfma_f32_16x16x32_bf16(pl, vh, oacc[c], 0, 0, 0);
    }
  }

  // ---- exact LSE merge across the 4 waves
  if (l15 == 0) {
#pragma unroll
    for (int r = 0; r < 4; r++) {
      sOm[w][quad * 4 + r] = m_i[r];
      sOl[w][quad * 4 + r] = l_i[r];
    }
  }
  __syncthreads();
  float* myO = U + w * 1600;
#pragma unroll
  for (int r = 0; r < 4; r++) {
    int row = quad * 4 + r;
    float ms = fmaxf(fmaxf(sOm[0][row], sOm[1][row]),
                     fmaxf(sOm[2][row], sOm[3][row]));
    float f = __expf(m_i[r] - ms);
#pragma unroll
    for (int c = 0; c < 6; c++) myO[row * 100 + c * 16 + l15] = oacc[c][r] * f;
  }
  __syncthreads();
#pragma unroll
  for (int k = 0; k < 6; k++) {
    int e = k * 256 + tid;            // 1536 = 16 rows x 96 cols
    int row = e / 96, col = e - row * 96;
    if (row < qlen) {
      float ms = fmaxf(fmaxf(sOm[0][row], sOm[1][row]),
                       fmaxf(sOm[2][row], sOm[3][row]));
      float ls = sOl[0][row] * __expf(sOm[0][row] - ms)
               + sOl[1][row] * __expf(sOm[1][row] - ms)
               + sOl[2][row] * __expf(sOm[2][row] - ms)
               + sOl[3][row] * __expf(sOm[3][row] - ms);
      float sum = U[0 * 1600 + row * 100 + col] + U[1 * 1600 + row * 100 + col]
                + U[2 * 1600 + row * 100 + col] + U[3 * 1600 + row * 100 + col];
      outp[(base + q0 + row) * DIM + h * HD + col] = sum / ls;
    }
  }
}

// ---------------------------------------------------------------- layernorm
__global__ __launch_bounds__(256) void k_ln(const float* __restrict__ x,
                                            const float* __restrict__ g,
                                            const float* __restrict__ be,
                                            float* __restrict__ outp) {
  int row = blockIdx.x;
  const float* xr = x + (size_t)row * DIM;
  float v[3]; float s = 0.f;
#pragma unroll
  for (int i = 0; i < 3; i++) { v[i] = xr[threadIdx.x + (i << 8)]; s += v[i]; }
#pragma unroll
  for (int off = 1; off < 64; off <<= 1) s += __shfl_xor(s, off, 64);
  __shared__ float red[4];
  int wv = threadIdx.x >> 6;
  if ((threadIdx.x & 63) == 0) red[wv] = s;
  __syncthreads();
  float mu = (red[0] + red[1] + red[2] + red[3]) * (1.0f / 768.0f);
  float sq = 0.f;
#pragma unroll
  for (int i = 0; i < 3; i++) { float d2 = v[i] - mu; sq += d2 * d2; }
#pragma unroll
  for (int off = 1; off < 64; off <<= 1) sq += __shfl_xor(sq, off, 64);
  __syncthreads();
  if ((threadIdx.x & 63) == 0) red[wv] = sq;
  __syncthreads();
  float var = (red[0] + red[1] + red[2] + red[3]) * (1.0f / 768.0f);
  float rstd = rsqrtf(var + 1e-5f);
  float* orow = outp + (size_t)row * DIM;
#pragma unroll
  for (int i = 0; i < 3; i++) {
    int d = threadIdx.x + (i << 8);
    orow[d] = (v[i] - mu) * rstd * g[d] + be[d];
  }
}

// ---------------------------------------------------------------- launch
extern "C" void kernel_launch(void* const* d_in, const int* in_sizes, int n_in,
                              void* d_out, int out_size, void* d_ws, size_t ws_size,
                              hipStream_t stream) {
  (void)in_sizes; (void)n_in; (void)out_size; (void)ws_size;
  const float* seq0 = (const float*)d_in[0];
  const float* seq1 = (const float*)d_in[1];
  const float* seq2 = (const float*)d_in[2];

  const size_t NX   = (size_t)ROWS * DIM;    // 4,915,200
  const size_t NQKV = (size_t)ROWS * QKVD;   // 14,745,600
  const int WIN_N   = QKVD * DIM;            // 1,769,472
  const int WOUT_N  = DIM * DIM;             //   589,824

  // ws layout (~128.2 MiB): x0 | qkv | att | X | S
  // time-shared overlays (all disjoint in time, per-layer order):
  //   x0 region (2*NX u16): embed floats (l0 only) -> Kt planes (attn) -> P2
  //   att region: P1 planes (QKV gemm) -> attention output
  //   X region: layer activation -> Vtlo (attn) -> next activation
  //   S region (VTN u16): WP planes (gemms) <-> Vthi (attn)
  float* x0   = (float*)d_ws;
  float* qkvb = x0   + NX;
  float* att  = qkvb + NQKV;
  float* X    = att  + NX;
  u16*   S    = (u16*)(X + NX);
  u16*   WPh  = S;          u16* WPl  = S + WIN_N;
  u16*   Vthi = S;          u16* Vtlo = (u16*)X;
  u16*   Kthi = (u16*)x0;   u16* Ktlo = Kthi + NX;
  u16*   P1h  = (u16*)att;  u16* P1l  = P1h + NX;
  u16*   P2h  = (u16*)x0;   u16* P2l  = P2h + NX;

  for (int g = 0; g < 2; g++) {           // g=0: inter, g=1: intra
    const float* w_in  = (const float*)d_in[3 + 6 * g];
    const float* b_in  = (const float*)d_in[4 + 6 * g];
    const float* w_out = (const float*)d_in[5 + 6 * g];
    const float* b_out = (const float*)d_in[6 + 6 * g];
    const float* ln_g  = (const float*)d_in[7 + 6 * g];
    const float* ln_b  = (const float*)d_in[8 + 6 * g];

    k_embed<<<ROWS, 256, 0, stream>>>(seq0, seq1, seq2, x0);

    for (int l = 0; l < 4; l++) {
      const float* xin = (l == 0) ? x0 : X;
      k_conv<<<(int)(NX / 8 / 256), 256, 0, stream>>>(xin, P1h, P1l, (int)(NX / 8));
      k_conv<<<WIN_N / 8 / 256, 256, 0, stream>>>(
          w_in + (size_t)l * WIN_N, WPh, WPl, WIN_N / 8);
      k_gemm_mfma<<<dim3(QKVD / 128, ROWS / 128), 256, 0, stream>>>(
          P1h, P1l, WPh, WPl, b_in + (size_t)l * QKVD, qkvb, ROWS, QKVD, DIM);

      k_convkv<<<13 * 64, 256, 0, stream>>>(qkvb, Kthi, Ktlo, Vthi, Vtlo);
      k_attn<<<52 * 64, 256, 0, stream>>>(qkvb, Kthi, Ktlo, Vthi, Vtlo, att, g);

      k_conv<<<(int)(NX / 8 / 256), 256, 0, stream>>>(att, P2h, P2l, (int)(NX / 8));
      k_conv<<<WOUT_N / 8 / 256, 256, 0, stream>>>(
          w_out + (size_t)l * WOUT_N, WPh, WPl, WOUT_N / 8);
      k_gemm_mfma<<<dim3(DIM / 128, ROWS / 128), 256, 0, stream>>>(
          P2h, P2l, WPh, WPl, b_out + (size_t)l * DIM, X, ROWS, DIM, DIM);
    }
    k_ln<<<ROWS, 256, 0, stream>>>(X, ln_g, ln_b,
                                   (float*)d_out + (size_t)g * ROWS * DIM);
  }
}

// Round 5
// 1812.165 us; speedup vs baseline: 1.3948x; 1.3948x over previous
//
#include <hip/hip_runtime.h>
#include <math.h>

// FusionShiftingGraph: two 4-layer no-residual transformer stacks + final LN.
// Round 5: r3 attention structure (64-row q-tiles, shared LDS K/V) with
// fragment-ready pre-tiled K/V planes -> pure async16 staging + conflict-free
// ds_read_b128 (dword stride 4*l15 mod 32), zero in-loop conversion VALU.
// Fused conversions: k_attn epilogue emits 2-plane A-operand output; out-proj
// GEMM epilogue emits next layer's A-planes (floats only at l==3).
//
// Segments: [0,50) [50,425) [425,800).  B=8, N=800, D=768, H=8, hd=96.

#define NTOK 800
#define ROWS 6400          // B*N
#define DIM 768
#define QKVD 2304
#define HD 96
#define NTILE 26           // padded key space 832 = 26 x 32
#define BHSTR 79872        // per-bh plane stride (26*384*8 u16)

typedef unsigned short u16;
typedef unsigned int u32;
using bf16x8 = __attribute__((ext_vector_type(8))) short;   // 8 bf16 (4 VGPRs)
using f32x4  = __attribute__((ext_vector_type(4))) float;

__device__ __forceinline__ u16 f2bf(float x) {            // RNE fp32->bf16
  union { float f; u32 u; } v; v.f = x;
  u32 r = v.u + 0x7fffu + ((v.u >> 16) & 1u);
  return (u16)(r >> 16);
}
__device__ __forceinline__ float bf2f(u16 h) {
  union { u32 u; float f; } v; v.u = ((u32)h) << 16;
  return v.f;
}
__device__ __forceinline__ u32 asu(float x) { union { float f; u32 u; } v; v.f = x; return v.u; }
__device__ __forceinline__ float asf(u32 x) { union { u32 u; float f; } v; v.u = x; return v.f; }
__device__ __forceinline__ void async16(const u16* g, u16* l) {
  __builtin_amdgcn_global_load_lds((const __attribute__((address_space(1))) u32*)g,
                                   (__attribute__((address_space(3))) u32*)l,
                                   16, 0, 0);
}

// ---------------------------------------------------------------- embed
__global__ __launch_bounds__(256) void k_embed(const float* __restrict__ s0,
                                               const float* __restrict__ s1,
                                               const float* __restrict__ s2,
                                               float* __restrict__ x) {
  int row = blockIdx.x;            // 0..6399
  int b = row / NTOK, n = row % NTOK;
  const float* src; int ln;
  if (n < 50)       { src = s0 + ((size_t)b * 50  + n)         * DIM; ln = n; }
  else if (n < 425) { src = s1 + ((size_t)b * 375 + (n - 50))  * DIM; ln = n - 50; }
  else              { src = s2 + ((size_t)b * 375 + (n - 425)) * DIM; ln = n - 425; }
  double p = (double)(ln + 2);     // fairseq: positions start at padding_idx+1=2
  const double negk = -(9.210340371976184 / 383.0);  // -ln(10000)/(half-1)
  float* dst = x + (size_t)row * DIM;
  for (int i = 0; i < 3; i++) {
    int d = threadIdx.x + (i << 8);
    int dd = (d < 384) ? d : d - 384;
    double ang = p * exp((double)dd * negk);
    float pe = (float)((d < 384) ? sin(ang) : cos(ang));
    dst[d] = 27.712812921102035f * src[d] + pe;   // sqrt(768)*s + pe
  }
}

// ------------------------------------------------- fp32 -> (hi,lo) bf16 planes
__global__ __launch_bounds__(256) void k_conv(const float* __restrict__ x,
                                              u16* __restrict__ hi,
                                              u16* __restrict__ lo, int n8) {
  int i = blockIdx.x * 256 + threadIdx.x;   // 8 elems / thread
  if (i >= n8) return;
  float4 a = ((const float4*)x)[i * 2];
  float4 b = ((const float4*)x)[i * 2 + 1];
  float v[8] = {a.x, a.y, a.z, a.w, b.x, b.y, b.z, b.w};
  u32 hp[4], lp[4];
#pragma unroll
  for (int j = 0; j < 4; j++) {
    u16 h0 = f2bf(v[2 * j]), h1 = f2bf(v[2 * j + 1]);
    u16 l0 = f2bf(v[2 * j] - bf2f(h0));
    u16 l1 = f2bf(v[2 * j + 1] - bf2f(h1));
    hp[j] = (u32)h0 | ((u32)h1 << 16);
    lp[j] = (u32)l0 | ((u32)l1 << 16);
  }
  ((uint4*)hi)[i] = make_uint4(hp[0], hp[1], hp[2], hp[3]);
  ((uint4*)lo)[i] = make_uint4(lp[0], lp[1], lp[2], lp[3]);
}

// ------------------------------------------- split-bf16 MFMA NT GEMM
// C = A*W^T + bias; optional fp32 store (wantF) and/or 2-plane bf16 store
// (Chi/Clo non-null) for feeding the next GEMM's A-operand directly.
__global__ __launch_bounds__(256) void k_gemm_mfma(
    const u16* __restrict__ Ah, const u16* __restrict__ Al,
    const u16* __restrict__ Bh, const u16* __restrict__ Bl,
    const float* __restrict__ bias, float* __restrict__ C,
    u16* __restrict__ Chi, u16* __restrict__ Clo, int wantF,
    int M, int N, int K) {
  __shared__ __align__(16) u16 sm[4 * 4096];       // Ah | Al | Bh | Bl
  int tid = threadIdx.x;
  int wave = tid >> 6, lane = tid & 63;
  int m0 = blockIdx.y << 7, n0 = blockIdx.x << 7;
  int wr = wave >> 1, wc = wave & 1;
  int l15 = lane & 15, quad = lane >> 4;

  f32x4 acc[4][4];
#pragma unroll
  for (int i = 0; i < 4; i++)
#pragma unroll
    for (int j = 0; j < 4; j++) acc[i][j] = (f32x4){0.f, 0.f, 0.f, 0.f};

  const u16* srcs[4] = {Ah + (size_t)m0 * K, Al + (size_t)m0 * K,
                        Bh + (size_t)n0 * K, Bl + (size_t)n0 * K};
  int li0 = wave * 64 + lane;
  int li1 = li0 + 256;
  int r0 = li0 >> 2, q0 = (li0 & 3) ^ ((r0 >> 1) & 3);
  int r1 = li1 >> 2, q1 = (li1 & 3) ^ ((r1 >> 1) & 3);
  size_t g0 = (size_t)r0 * K + q0 * 8;
  size_t g1 = (size_t)r1 * K + q1 * 8;

  for (int kt = 0; kt < K; kt += 32) {
    __syncthreads();
#pragma unroll
    for (int ri = 0; ri < 4; ri++) {
      const u16* s = srcs[ri] + kt;
      async16(s + g0, &sm[ri * 4096 + wave * 512]);
      async16(s + g1, &sm[ri * 4096 + 2048 + wave * 512]);
    }
    __syncthreads();

    bf16x8 ah[4], al[4], bh[4], bl[4];
#pragma unroll
    for (int i = 0; i < 4; i++) {
      int ra = wr * 64 + i * 16 + l15;
      int qa = (quad ^ ((ra >> 1) & 3)) * 8;
      ah[i] = *(const bf16x8*)&sm[0 * 4096 + ra * 32 + qa];
      al[i] = *(const bf16x8*)&sm[1 * 4096 + ra * 32 + qa];
      int rb = wc * 64 + i * 16 + l15;
      int qb = (quad ^ ((rb >> 1) & 3)) * 8;
      bh[i] = *(const bf16x8*)&sm[2 * 4096 + rb * 32 + qb];
      bl[i] = *(const bf16x8*)&sm[3 * 4096 + rb * 32 + qb];
    }
#pragma unroll
    for (int i = 0; i < 4; i++)
#pragma unroll
      for (int j = 0; j < 4; j++) {
        acc[i][j] = __builtin_amdgcn_mfma_f32_16x16x32_bf16(ah[i], bh[j], acc[i][j], 0, 0, 0);
        acc[i][j] = __builtin_amdgcn_mfma_f32_16x16x32_bf16(ah[i], bl[j], acc[i][j], 0, 0, 0);
        acc[i][j] = __builtin_amdgcn_mfma_f32_16x16x32_bf16(al[i], bh[j], acc[i][j], 0, 0, 0);
      }
  }
#pragma unroll
  for (int i = 0; i < 4; i++) {
    int row0 = m0 + wr * 64 + i * 16 + quad * 4;
#pragma unroll
    for (int j = 0; j < 4; j++) {
      int col = n0 + wc * 64 + j * 16 + l15;
      float bv = bias[col];
#pragma unroll
      for (int r = 0; r < 4; r++) {
        size_t idx = (size_t)(row0 + r) * N + col;
        float v = acc[i][j][r] + bv;
        if (wantF) C[idx] = v;
        if (Chi) {
          u16 hu = f2bf(v);
          Chi[idx] = hu;
          Clo[idx] = f2bf(v - bf2f(hu));
        }
      }
    }
  }
}

// ------------------------------------------- K/V conversion -> tiled planes
// Kt[bh][tile26][chunk=(df*4+quad)*32+key][8]:  K[n=key'-off][df*32+quad*8+j]
// Vt[bh][tile26][chunk=quad*96+d][8]:           V[key'=tile*32+quad*8+j][d]
// trunc 2-plane bf16, pads zeroed. Grid: 13 (64-key chunks) x 64 bh.
__global__ __launch_bounds__(256) void k_convkv(const float* __restrict__ qkv,
                                                u16* __restrict__ Kthi,
                                                u16* __restrict__ Ktlo,
                                                u16* __restrict__ Vthi,
                                                u16* __restrict__ VtloA,
                                                u16* __restrict__ VtloB) {
  int ck = blockIdx.x >> 6;        // 0..12
  int bh = blockIdx.x & 63;
  int b = bh >> 3, h = bh & 7;
  int kt = ck << 6;
  int ve  = kt < 64 ? 50 : kt < 448 ? 439 : 823;   // valid end (padded coords)
  int off = kt < 64 ? 0  : kt < 448 ? 14  : 23;    // key' - off = real n
  __shared__ float Ls[96 * 68];
  int tid = threadIdx.x;
  size_t base = (size_t)b * NTOK;
  u16* vtlo = (bh < 32) ? (VtloA + (size_t)bh * BHSTR)
                        : (VtloB + (size_t)(bh - 32) * BHSTR);
  u16* kthi = Kthi + (size_t)bh * BHSTR;
  u16* ktlo = Ktlo + (size_t)bh * BHSTR;
  u16* vthi = Vthi + (size_t)bh * BHSTR;

  // ---- K: fragment-order convert
#pragma unroll
  for (int i = 0; i < 3; i++) {
    int c = i * 256 + tid;            // 768 = 64 keys x 12 d-chunks
    int key = c / 12, dc = c - key * 12;
    int kp = kt + key;
    uint4 hi4 = make_uint4(0, 0, 0, 0), lo4 = make_uint4(0, 0, 0, 0);
    if (kp < ve) {
      const float* p = qkv + (base + kp - off) * QKVD + DIM + h * HD + dc * 8;
      float4 a = *(const float4*)p;
      float4 e = *(const float4*)(p + 4);
      float xs[8] = {a.x, a.y, a.z, a.w, e.x, e.y, e.z, e.w};
      u32 hp[4], lp[4];
#pragma unroll
      for (int j = 0; j < 4; j++) {
        u32 b0 = asu(xs[2 * j]), b1 = asu(xs[2 * j + 1]);
        hp[j] = (b0 >> 16) | (b1 & 0xffff0000u);
        float l0 = xs[2 * j] - asf(b0 & 0xffff0000u);
        float l1 = xs[2 * j + 1] - asf(b1 & 0xffff0000u);
        lp[j] = (asu(l0) >> 16) | (asu(l1) & 0xffff0000u);
      }
      hi4 = make_uint4(hp[0], hp[1], hp[2], hp[3]);
      lo4 = make_uint4(lp[0], lp[1], lp[2], lp[3]);
    }
    int tile = (kt >> 5) + (key >> 5), key32 = key & 31;
    size_t go = ((size_t)tile * 384 + dc * 32 + key32) * 8;
    *(uint4*)(kthi + go) = hi4;
    *(uint4*)(ktlo + go) = lo4;
  }

  // ---- V: transpose via LDS, fragment-order emit
#pragma unroll
  for (int i = 0; i < 6; i++) {
    int c = i * 256 + tid;            // 1536 = 64 keys x 24 float4-chunks
    int key = c / 24, fc = c - key * 24;
    int kp = kt + key;
    float4 v = make_float4(0.f, 0.f, 0.f, 0.f);
    if (kp < ve)
      v = *(const float4*)(qkv + (base + kp - off) * QKVD + 2 * DIM + h * HD + fc * 4);
    Ls[(fc * 4 + 0) * 68 + key] = v.x;
    Ls[(fc * 4 + 1) * 68 + key] = v.y;
    Ls[(fc * 4 + 2) * 68 + key] = v.z;
    Ls[(fc * 4 + 3) * 68 + key] = v.w;
  }
  __syncthreads();
#pragma unroll
  for (int i = 0; i < 3; i++) {
    int c = i * 256 + tid;            // 768 = 2 tiles x 384 chunks
    int tl = c / 384, cc = c - tl * 384;
    int quad = cc / 96, d = cc - quad * 96;
    const float* ls = &Ls[d * 68 + tl * 32 + quad * 8];
    u32 hp[4], lp[4];
#pragma unroll
    for (int j = 0; j < 4; j++) {
      float x0v = ls[2 * j], x1v = ls[2 * j + 1];
      u32 b0 = asu(x0v), b1 = asu(x1v);
      hp[j] = (b0 >> 16) | (b1 & 0xffff0000u);
      float l0 = x0v - asf(b0 & 0xffff0000u);
      float l1 = x1v - asf(b1 & 0xffff0000u);
      lp[j] = (asu(l0) >> 16) | (asu(l1) & 0xffff0000u);
    }
    size_t go = ((size_t)((kt >> 5) + tl) * 384 + cc) * 8;
    *(uint4*)(vthi + go) = make_uint4(hp[0], hp[1], hp[2], hp[3]);
    *(uint4*)(vtlo + go) = make_uint4(lp[0], lp[1], lp[2], lp[3]);
  }
}

// ------------------------------------------- MFMA flash attention (r3 shape)
// 13 q-tiles x 64 bh (t-major for XCD L2 locality). 64 q-rows/block, 4 waves
// each own 16 rows. Per 32-key tile: 6 contiguous async16/thread staging of
// fragment-ready K/V planes, then pure MFMA + softmax. Output written as RNE
// 2-plane bf16 A-operand planes (feeds out-proj GEMM directly).
__global__ __launch_bounds__(256) void k_attn(const float* __restrict__ qkv,
                                              const u16* __restrict__ Kthi,
                                              const u16* __restrict__ Ktlo,
                                              const u16* __restrict__ Vthi,
                                              const u16* __restrict__ VtloA,
                                              const u16* __restrict__ VtloB,
                                              u16* __restrict__ ohi,
                                              u16* __restrict__ olo,
                                              int intra) {
  int t  = blockIdx.x >> 6;        // 0..12
  int bh = blockIdx.x & 63;
  int b = bh >> 3, h = bh & 7;

  int seg, q0, qlen;
  if (t == 0)      { seg = 0; q0 = 0;                  qlen = 50; }
  else if (t <= 6) { seg = 1; q0 = 50 + ((t - 1) << 6);  qlen = (425 - q0 < 64) ? (425 - q0) : 64; }
  else             { seg = 2; q0 = 425 + ((t - 7) << 6); qlen = (800 - q0 < 64) ? (800 - q0) : 64; }

  // key ranges in padded coords
  int r0s, r0e, r1s = 0, r1e = 0;
  if (intra) {
    r0s = (seg == 0) ? 0 : (seg == 1) ? 64 : 448;
    r0e = (seg == 0) ? 64 : (seg == 1) ? 448 : 832;
  } else {
    if (seg == 0)      { r0s = 64; r0e = 832; }
    else if (seg == 1) { r0s = 0;  r0e = 64;  r1s = 448; r1e = 832; }
    else               { r0s = 0;  r0e = 448; }
  }
  int n0t = (r0e - r0s) >> 5, n1t = (r1e - r1s) >> 5, nkt = n0t + n1t;

  __shared__ __align__(16) u16 sKV[4 * 3072];   // Khi | Klo | Vhi | Vlo (24KB)
  __shared__ u32 sP[4][16 * 36];                // per-wave P transpose

  int tid = threadIdx.x;
  int w = tid >> 6, lane = tid & 63, l15 = lane & 15, quad = lane >> 4;
  size_t base = (size_t)b * NTOK;
  const float sm0 = 0.10206207261596575f;   // 96^-0.5

  // staging source/dest precompute (loop-invariant per thread)
  const u16* sp0 = Kthi + (size_t)bh * BHSTR;
  const u16* sp1 = Ktlo + (size_t)bh * BHSTR;
  const u16* sp2 = Vthi + (size_t)bh * BHSTR;
  const u16* sp3 = (bh < 32) ? (VtloA + (size_t)bh * BHSTR)
                             : (VtloB + (size_t)(bh - 32) * BHSTR);
  const u16* sptr[6];
  u16* dptr[6];
#pragma unroll
  for (int j = 0; j < 6; j++) {
    int c = j * 256 + tid;           // 0..1535
    int rg = c / 384, cc = c - rg * 384;
    const u16* pb = rg == 0 ? sp0 : rg == 1 ? sp1 : rg == 2 ? sp2 : sp3;
    sptr[j] = pb + cc * 8;
    dptr[j] = &sKV[c * 8];
  }

  // ---- Q fragments (RNE 2-plane, pre-scaled) — wave w owns rows w*16..+15
  bf16x8 qh[3], ql[3];
  {
    int q = q0 + w * 16 + l15; if (q > 799) q = 799;
    const float* qp = qkv + (base + q) * QKVD + h * HD;
#pragma unroll
    for (int df = 0; df < 3; df++) {
      float4 x0v = *(const float4*)(qp + df * 32 + quad * 8);
      float4 x1v = *(const float4*)(qp + df * 32 + quad * 8 + 4);
      float xs[8] = {x0v.x, x0v.y, x0v.z, x0v.w, x1v.x, x1v.y, x1v.z, x1v.w};
#pragma unroll
      for (int j = 0; j < 8; j++) {
        float x = xs[j] * sm0;
        u16 hu = f2bf(x);
        u16 lu = f2bf(x - bf2f(hu));
        qh[df][j] = (short)hu; ql[df][j] = (short)lu;
      }
    }
  }

  f32x4 oacc[6];
#pragma unroll
  for (int c = 0; c < 6; c++) oacc[c] = (f32x4){0.f, 0.f, 0.f, 0.f};
  float m_i[4], l_i[4];
#pragma unroll
  for (int r = 0; r < 4; r++) { m_i[r] = -1e30f; l_i[r] = 0.f; }

  u32* sPw = sP[w];

  for (int it = 0; it < nkt; it++) {
    int kt = (it < n0t) ? (r0s + (it << 5)) : (r1s + ((it - n0t) << 5));
    int ve = kt < 64 ? 50 : kt < 448 ? 439 : 823;

    __syncthreads();                 // all waves done with prev tile
    size_t toff = (size_t)(kt >> 5) * 3072;
#pragma unroll
    for (int j = 0; j < 6; j++) async16(sptr[j] + toff, dptr[j]);
    __syncthreads();                 // staging visible (vmcnt drained)

    // ---- S = Q K^T  (K frags: dword bank = 4*l15 mod 32, conflict-free)
    f32x4 Sf[2];
#pragma unroll
    for (int h2 = 0; h2 < 2; h2++) {
      f32x4 s = (f32x4){0.f, 0.f, 0.f, 0.f};
#pragma unroll
      for (int df = 0; df < 3; df++) {
        int co = ((df * 4 + quad) * 32 + h2 * 16 + l15) * 8;
        bf16x8 kh = *(const bf16x8*)&sKV[co];
        bf16x8 kl = *(const bf16x8*)&sKV[3072 + co];
        s = __builtin_amdgcn_mfma_f32_16x16x32_bf16(qh[df], kh, s, 0, 0, 0);
        s = __builtin_amdgcn_mfma_f32_16x16x32_bf16(ql[df], kh, s, 0, 0, 0);
        s = __builtin_amdgcn_mfma_f32_16x16x32_bf16(qh[df], kl, s, 0, 0, 0);
      }
      Sf[h2] = s;
    }
    if (kt + l15 >= ve)      Sf[0] = (f32x4){-1e30f, -1e30f, -1e30f, -1e30f};
    if (kt + 16 + l15 >= ve) Sf[1] = (f32x4){-1e30f, -1e30f, -1e30f, -1e30f};

    // ---- online softmax
    float mx[4], al[4], ps0[4], ps1[4], rs[4];
#pragma unroll
    for (int r = 0; r < 4; r++) mx[r] = fmaxf(Sf[0][r], Sf[1][r]);
#pragma unroll
    for (int o = 1; o < 16; o <<= 1)
#pragma unroll
      for (int r = 0; r < 4; r++) mx[r] = fmaxf(mx[r], __shfl_xor(mx[r], o, 64));
#pragma unroll
    for (int r = 0; r < 4; r++) {
      float mn = fmaxf(m_i[r], mx[r]);
      al[r] = __expf(m_i[r] - mn);
      m_i[r] = mn;
      ps0[r] = __expf(Sf[0][r] - mn);
      ps1[r] = __expf(Sf[1][r] - mn);
      rs[r] = ps0[r] + ps1[r];
    }
#pragma unroll
    for (int o = 1; o < 16; o <<= 1)
#pragma unroll
      for (int r = 0; r < 4; r++) rs[r] += __shfl_xor(rs[r], o, 64);
#pragma unroll
    for (int r = 0; r < 4; r++) l_i[r] = l_i[r] * al[r] + rs[r];

    // ---- pack P (trunc 2-plane), transpose via per-wave LDS (intra-wave)
#pragma unroll
    for (int r = 0; r < 4; r++) {
      u32 b0 = asu(ps0[r]);
      float lo0 = ps0[r] - asf(b0 & 0xffff0000u);
      sPw[(quad * 4 + r) * 36 + l15] = (b0 >> 16) | (asu(lo0) & 0xffff0000u);
      u32 b1 = asu(ps1[r]);
      float lo1 = ps1[r] - asf(b1 & 0xffff0000u);
      sPw[(quad * 4 + r) * 36 + 16 + l15] = (b1 >> 16) | (asu(lo1) & 0xffff0000u);
    }
    asm volatile("" ::: "memory");   // intra-wave LDS in-order; block reordering
    uint4 t0 = *(const uint4*)&sPw[l15 * 36 + quad * 8];
    uint4 t1 = *(const uint4*)&sPw[l15 * 36 + quad * 8 + 4];
    u32 tt[8] = {t0.x, t0.y, t0.z, t0.w, t1.x, t1.y, t1.z, t1.w};
    bf16x8 ph, pl;
#pragma unroll
    for (int j = 0; j < 8; j++) {
      ph[j] = (short)(tt[j] & 0xffffu);
      pl[j] = (short)(tt[j] >> 16);
    }

    // ---- rescale O, then O += P V (V frags conflict-free)
    f32x4 alv = {al[0], al[1], al[2], al[3]};
#pragma unroll
    for (int c = 0; c < 6; c++) oacc[c] *= alv;
#pragma unroll
    for (int c = 0; c < 6; c++) {
      int co = (quad * 96 + c * 16 + l15) * 8;
      bf16x8 vh = *(const bf16x8*)&sKV[2 * 3072 + co];
      bf16x8 vl = *(const bf16x8*)&sKV[3 * 3072 + co];
      oacc[c] = __builtin_amdgcn_mfma_f32_16x16x32_bf16(ph, vh, oacc[c], 0, 0, 0);
      oacc[c] = __builtin_amdgcn_mfma_f32_16x16x32_bf16(ph, vl, oacc[c], 0, 0, 0);
      oacc[c] = __builtin_amdgcn_mfma_f32_16x16x32_bf16(pl, vh, oacc[c], 0, 0, 0);
    }
  }

  // ---- epilogue: RNE 2-plane A-operand output
  float inv[4];
#pragma unroll
  for (int r = 0; r < 4; r++) inv[r] = 1.0f / l_i[r];
#pragma unroll
  for (int c = 0; c < 6; c++)
#pragma unroll
    for (int r = 0; r < 4; r++) {
      int rl = w * 16 + quad * 4 + r;
      if (rl < qlen) {
        float v = oacc[c][r] * inv[r];
        size_t idx = (base + q0 + rl) * DIM + h * HD + c * 16 + l15;
        u16 hu = f2bf(v);
        ohi[idx] = hu;
        olo[idx] = f2bf(v - bf2f(hu));
      }
    }
}

// ---------------------------------------------------------------- layernorm
__global__ __launch_bounds__(256) void k_ln(const float* __restrict__ x,
                                            const float* __restrict__ g,
                                            const float* __restrict__ be,
                                            float* __restrict__ outp) {
  int row = blockIdx.x;
  const float* xr = x + (size_t)row * DIM;
  float v[3]; float s = 0.f;
#pragma unroll
  for (int i = 0; i < 3; i++) { v[i] = xr[threadIdx.x + (i << 8)]; s += v[i]; }
#pragma unroll
  for (int off = 1; off < 64; off <<= 1) s += __shfl_xor(s, off, 64);
  __shared__ float red[4];
  int wv = threadIdx.x >> 6;
  if ((threadIdx.x & 63) == 0) red[wv] = s;
  __syncthreads();
  float mu = (red[0] + red[1] + red[2] + red[3]) * (1.0f / 768.0f);
  float sq = 0.f;
#pragma unroll
  for (int i = 0; i < 3; i++) { float d2 = v[i] - mu; sq += d2 * d2; }
#pragma unroll
  for (int off = 1; off < 64; off <<= 1) sq += __shfl_xor(sq, off, 64);
  __syncthreads();
  if ((threadIdx.x & 63) == 0) red[wv] = sq;
  __syncthreads();
  float var = (red[0] + red[1] + red[2] + red[3]) * (1.0f / 768.0f);
  float rstd = rsqrtf(var + 1e-5f);
  float* orow = outp + (size_t)row * DIM;
#pragma unroll
  for (int i = 0; i < 3; i++) {
    int d = threadIdx.x + (i << 8);
    orow[d] = (v[i] - mu) * rstd * g[d] + be[d];
  }
}

// ---------------------------------------------------------------- launch
extern "C" void kernel_launch(void* const* d_in, const int* in_sizes, int n_in,
                              void* d_out, int out_size, void* d_ws, size_t ws_size,
                              hipStream_t stream) {
  (void)in_sizes; (void)n_in; (void)out_size; (void)ws_size;
  const float* seq0 = (const float*)d_in[0];
  const float* seq1 = (const float*)d_in[1];
  const float* seq2 = (const float*)d_in[2];

  const size_t NX   = (size_t)ROWS * DIM;    // 4,915,200
  const size_t NQKV = (size_t)ROWS * QKVD;   // 14,745,600
  const int WIN_N   = QKVD * DIM;            // 1,769,472
  const int WOUT_N  = DIM * DIM;             //   589,824
  const size_t PLN  = (size_t)64 * BHSTR;    // 5,111,808 u16 per plane

  // ws (128.19 MiB): x0 | qkv | att | X | S.  Time-shared overlays per layer:
  //   x0 region (2NX u16): P1 planes (A of QKV gemm) -> Kthi + VtloA (attn)
  //   att region (2NX u16): embed floats (pre-l0) -> P2 planes (attn out = A
  //                         of out-proj gemm)
  //   X region (2NX u16): Ktlo + VtloB (attn); X floats written only at l==3
  //   S region (PLN u16): WP planes (gemms) <-> Vthi (attn)
  float* x0   = (float*)d_ws;
  float* qkvb = x0   + NX;
  float* att  = qkvb + NQKV;
  float* X    = att  + NX;
  u16*   S    = (u16*)(X + NX);
  u16*   WPh  = S;            u16* WPl  = S + WIN_N;
  u16*   Vthi = S;
  u16*   P1h  = (u16*)x0;     u16* P1l  = P1h + NX;
  u16*   P2h  = (u16*)att;    u16* P2l  = P2h + NX;
  u16*   Kthi = (u16*)x0;     u16* VtloA = Kthi + PLN;   // 32 bh
  u16*   Ktlo = (u16*)X;      u16* VtloB = Ktlo + PLN;   // 32 bh

  for (int g = 0; g < 2; g++) {           // g=0: inter, g=1: intra
    const float* w_in  = (const float*)d_in[3 + 6 * g];
    const float* b_in  = (const float*)d_in[4 + 6 * g];
    const float* w_out = (const float*)d_in[5 + 6 * g];
    const float* b_out = (const float*)d_in[6 + 6 * g];
    const float* ln_g  = (const float*)d_in[7 + 6 * g];
    const float* ln_b  = (const float*)d_in[8 + 6 * g];

    k_embed<<<ROWS, 256, 0, stream>>>(seq0, seq1, seq2, att);

    for (int l = 0; l < 4; l++) {
      if (l == 0)
        k_conv<<<(int)(NX / 8 / 256), 256, 0, stream>>>(att, P1h, P1l, (int)(NX / 8));
      k_conv<<<WIN_N / 8 / 256, 256, 0, stream>>>(
          w_in + (size_t)l * WIN_N, WPh, WPl, WIN_N / 8);
      k_gemm_mfma<<<dim3(QKVD / 128, ROWS / 128), 256, 0, stream>>>(
          P1h, P1l, WPh, WPl, b_in + (size_t)l * QKVD, qkvb,
          nullptr, nullptr, 1, ROWS, QKVD, DIM);

      k_convkv<<<13 * 64, 256, 0, stream>>>(qkvb, Kthi, Ktlo, Vthi, VtloA, VtloB);
      k_attn<<<13 * 64, 256, 0, stream>>>(qkvb, Kthi, Ktlo, Vthi, VtloA, VtloB,
                                          P2h, P2l, g);

      k_conv<<<WOUT_N / 8 / 256, 256, 0, stream>>>(
          w_out + (size_t)l * WOUT_N, WPh, WPl, WOUT_N / 8);
      k_gemm_mfma<<<dim3(DIM / 128, ROWS / 128), 256, 0, stream>>>(
          P2h, P2l, WPh, WPl, b_out + (size_t)l * DIM, X,
          P1h, P1l, (l == 3) ? 1 : 0, ROWS, DIM, DIM);
    }
    k_ln<<<ROWS, 256, 0, stream>>>(X, ln_g, ln_b,
                                   (float*)d_out + (size_t)g * ROWS * DIM);
  }
}